// Round 2
// baseline (161.242 us; speedup 1.0000x reference)
//
#include <hip/hip_runtime.h>

// out[m,u] = x2[m] + w2[u] - 2 * sum_k x[m,k] * w[k,u]
// x[8*4096, 128] f32, w[128, 1024] f32, out[32768, 1024] f32
#define M_TOT 32768
#define K_DIM 128
#define U_TOT 1024

#define BM 128
#define BN 128
#define BK 32

typedef short s16x8 __attribute__((ext_vector_type(8)));   // 8 bf16 as shorts (guide-verified)
typedef float f32x4 __attribute__((ext_vector_type(4)));

// round-to-nearest-even fp32 -> bf16 (as ushort)
__device__ inline unsigned int f2bf(float f) {
    union { float f; unsigned int u; } v; v.f = f;
    unsigned int r = v.u + 0x7FFFu + ((v.u >> 16) & 1u);
    return r >> 16;
}

// async global->LDS, 16B per lane; LDS dest = wave-uniform base + lane*16
__device__ inline void async_load16(const void* g, void* l) {
    __builtin_amdgcn_global_load_lds((const __attribute__((address_space(1))) void*)g,
                                     (__attribute__((address_space(3))) void*)l,
                                     16, 0, 0);
}

// One wave per row: x -> bf16 row-major + x2;  w -> w^T bf16 + w2.
__global__ __launch_bounds__(256) void prep_kernel(
    const float* __restrict__ x, const float* __restrict__ w,
    unsigned int* __restrict__ xb, unsigned int* __restrict__ wt,
    float* __restrict__ x2, float* __restrict__ w2)
{
    const int lane = threadIdx.x & 63;
    const int gw = (blockIdx.x << 2) + (threadIdx.x >> 6);
    if (gw < M_TOT) {
        const float2 v = ((const float2*)(x + (size_t)gw * K_DIM))[lane];
        float s = v.x * v.x + v.y * v.y;
        #pragma unroll
        for (int off = 32; off; off >>= 1) s += __shfl_xor(s, off);
        xb[gw * 64 + lane] = f2bf(v.x) | (f2bf(v.y) << 16);
        if (lane == 0) x2[gw] = s;
    } else if (gw < M_TOT + U_TOT) {
        const int u = gw - M_TOT;
        const float a = w[(size_t)(2 * lane) * U_TOT + u];
        const float b = w[(size_t)(2 * lane + 1) * U_TOT + u];
        float s = a * a + b * b;
        #pragma unroll
        for (int off = 32; off; off >>= 1) s += __shfl_xor(s, off);
        wt[u * 64 + lane] = f2bf(a) | (f2bf(b) << 16);
        if (lane == 0) w2[u] = s;
    }
}

// 128x128 tile, bf16 MFMA 16x16x32, global_load_lds staging.
// Grid: 256 m-tiles * 8 u-tiles = 2048 blocks of 256 threads (4 waves, 2x2).
__global__ __launch_bounds__(256) void gemm_kernel(
    const unsigned short* __restrict__ xb, const unsigned short* __restrict__ wt,
    const float* __restrict__ x2, const float* __restrict__ w2,
    float* __restrict__ out)
{
    // Linear LDS layout [row][k], stride BK=32 elems — NO padding (global_load_lds
    // writes base + lane*16; layout must be contiguous in lane order).
    __shared__ __align__(16) unsigned short As[BM * BK];
    __shared__ __align__(16) unsigned short Bs[BN * BK];

    const int tid = threadIdx.x;
    const int wv = tid >> 6;
    const int lane = tid & 63;
    const int m0 = (int)(blockIdx.x >> 3) * BM;
    const int u0 = (int)(blockIdx.x & 7) * BN;
    const int wm = (wv & 1) * 64;
    const int wn = (wv >> 1) * 64;
    const int col = lane & 15;
    const int quad = lane >> 4;
    const int srow = lane >> 2;          // staging row within 16-row group
    const int sch = (lane & 3) * 8;      // staging k-offset (8 bf16 = 16 B)

    f32x4 acc[4][4] = {};

    #pragma unroll
    for (int kt = 0; kt < 4; ++kt) {
        const int k0 = kt * BK;
        #pragma unroll
        for (int i = 0; i < 2; ++i) {
            const int rb = (wv * 2 + i) * 16;
            async_load16(xb + (size_t)(m0 + rb + srow) * K_DIM + k0 + sch, &As[rb * BK]);
            async_load16(wt + (size_t)(u0 + rb + srow) * K_DIM + k0 + sch, &Bs[rb * BK]);
        }
        __syncthreads();

        // A frag: A[m=lane&15][k=quad*8+j]; B frag: B[k=quad*8+j][n=lane&15] (w^T rows).
        s16x8 af[4], bfr[4];
        #pragma unroll
        for (int t = 0; t < 4; ++t) {
            af[t]  = *(const s16x8*)&As[(wm + t * 16 + col) * BK + quad * 8];
            bfr[t] = *(const s16x8*)&Bs[(wn + t * 16 + col) * BK + quad * 8];
        }
        #pragma unroll
        for (int a = 0; a < 4; ++a)
            #pragma unroll
            for (int b = 0; b < 4; ++b)
                acc[a][b] = __builtin_amdgcn_mfma_f32_16x16x32_bf16(af[a], bfr[b], acc[a][b], 0, 0, 0);
        __syncthreads();
    }

    // C/D layout: col = lane&15, row = quad*4 + reg.
    const int orow = quad * 4;
    #pragma unroll
    for (int a = 0; a < 4; ++a) {
        const int mb = m0 + wm + a * 16 + orow;
        float xs[4];
        #pragma unroll
        for (int r = 0; r < 4; ++r) xs[r] = x2[mb + r];
        #pragma unroll
        for (int b = 0; b < 4; ++b) {
            const int u = u0 + wn + b * 16 + col;
            const float wsq = w2[u];
            float* op = out + (size_t)mb * U_TOT + u;
            #pragma unroll
            for (int r = 0; r < 4; ++r)
                op[(size_t)r * U_TOT] = xs[r] + wsq - 2.0f * acc[a][b][r];
        }
    }
}

// Fallback (no workspace): correct fp32 path, used only if ws_size is too small.
// One block per output row m; threads cover u in 4 strides of 256.
__global__ __launch_bounds__(256) void fallback_kernel(
    const float* __restrict__ x, const float* __restrict__ w,
    float* __restrict__ out)
{
    __shared__ float xrow[K_DIM];
    const int m = blockIdx.x;
    const int tid = threadIdx.x;
    if (tid < K_DIM) xrow[tid] = x[(size_t)m * K_DIM + tid];
    __syncthreads();
    float x2 = 0.f;
    #pragma unroll
    for (int k = 0; k < K_DIM; ++k) x2 += xrow[k] * xrow[k];
    #pragma unroll
    for (int uu = 0; uu < 4; ++uu) {
        const int u = uu * 256 + tid;
        float dot = 0.f, w2 = 0.f;
        for (int k = 0; k < K_DIM; ++k) {
            const float wv = w[(size_t)k * U_TOT + u];
            dot += xrow[k] * wv;
            w2 += wv * wv;
        }
        out[(size_t)m * U_TOT + u] = x2 + w2 - 2.0f * dot;
    }
}

extern "C" void kernel_launch(void* const* d_in, const int* in_sizes, int n_in,
                              void* d_out, int out_size, void* d_ws, size_t ws_size,
                              hipStream_t stream) {
    const float* x = (const float*)d_in[0];
    const float* w = (const float*)d_in[1];
    float* out = (float*)d_out;

    // ws layout: xb bf16[32768*128] | wt bf16[1024*128] | x2 f32[32768] | w2 f32[1024]
    const size_t need = (size_t)M_TOT * K_DIM * 2 + (size_t)U_TOT * K_DIM * 2
                      + (size_t)M_TOT * 4 + (size_t)U_TOT * 4;
    if (ws_size < need) {                       // ws_size constant per session -> stable capture
        fallback_kernel<<<M_TOT, 256, 0, stream>>>(x, w, out);
        return;
    }

    unsigned short* xb = (unsigned short*)d_ws;
    unsigned short* wt = xb + (size_t)M_TOT * K_DIM;
    float* x2 = (float*)(wt + (size_t)U_TOT * K_DIM);
    float* w2 = x2 + M_TOT;

    prep_kernel<<<(M_TOT + U_TOT) / 4, 256, 0, stream>>>(x, w, (unsigned int*)xb,
                                                         (unsigned int*)wt, x2, w2);
    gemm_kernel<<<(M_TOT / BM) * (U_TOT / BN), 256, 0, stream>>>(xb, wt, x2, w2, out);
}